// Round 1
// baseline (1835.157 us; speedup 1.0000x reference)
//
#include <hip/hip_runtime.h>
#include <cstdint>
#include <math.h>

#define B_ 4
#define T_ 2048
#define C_ 512
#define H_ 8
#define HD_ 64
#define TOPK_ 32
#define ROWS_ (B_*H_*T_)   /* 65536 */
#define BT_ (B_*T_)        /* 8192 */

// ---------------- QKV projection GEMM: (8192x512)@(512x512), head-layout out --------
__global__ __launch_bounds__(256) void qkv_kernel(
    const float* __restrict__ x,
    const float* __restrict__ Wq, const float* __restrict__ bq,
    const float* __restrict__ Wk, const float* __restrict__ bk,
    const float* __restrict__ Wv, const float* __restrict__ bv,
    float* __restrict__ Q, float* __restrict__ K, float* __restrict__ V)
{
    const int which = blockIdx.z;
    const float* W    = (which == 0) ? Wq : (which == 1) ? Wk : Wv;
    const float* bias = (which == 0) ? bq : (which == 1) ? bk : bv;
    float* out        = (which == 0) ? Q  : (which == 1) ? K  : V;

    const int m0 = blockIdx.y * 128;
    const int n0 = blockIdx.x * 128;
    __shared__ float As[16][128];   // [k][m] transposed
    __shared__ float Bs[16][128];   // [k][n]
    float acc[8][8] = {};
    const int tid = threadIdx.x;
    const int tx = tid & 15, ty = tid >> 4;

    for (int k0 = 0; k0 < C_; k0 += 16) {
        #pragma unroll
        for (int i = 0; i < 2; ++i) {
            int t = tid + i * 256;           // 0..511
            int m  = t >> 2;                 // 0..127
            int kq = (t & 3) << 2;           // 0,4,8,12
            float4 a4 = *(const float4*)(x + (size_t)(m0 + m) * C_ + k0 + kq);
            As[kq + 0][m] = a4.x; As[kq + 1][m] = a4.y;
            As[kq + 2][m] = a4.z; As[kq + 3][m] = a4.w;
            int kk2 = t >> 5;                // 0..15
            int nq  = (t & 31) << 2;         // 0..124
            *(float4*)&Bs[kk2][nq] = *(const float4*)(W + (size_t)(k0 + kk2) * C_ + n0 + nq);
        }
        __syncthreads();
        #pragma unroll
        for (int k = 0; k < 16; ++k) {
            float a[8], b[8];
            *(float4*)&a[0] = *(const float4*)&As[k][ty * 8];
            *(float4*)&a[4] = *(const float4*)&As[k][ty * 8 + 4];
            *(float4*)&b[0] = *(const float4*)&Bs[k][tx * 8];
            *(float4*)&b[4] = *(const float4*)&Bs[k][tx * 8 + 4];
            #pragma unroll
            for (int i = 0; i < 8; ++i)
                #pragma unroll
                for (int j = 0; j < 8; ++j)
                    acc[i][j] += a[i] * b[j];
        }
        __syncthreads();
    }
    #pragma unroll
    for (int i = 0; i < 8; ++i) {
        int r = m0 + ty * 8 + i;
        int bb = r >> 11, t = r & (T_ - 1);
        #pragma unroll
        for (int j = 0; j < 8; j += 4) {
            int n = n0 + tx * 8 + j;
            int h = n >> 6, d = n & 63;
            float4 v4;
            v4.x = acc[i][j + 0] + bias[n + 0];
            v4.y = acc[i][j + 1] + bias[n + 1];
            v4.z = acc[i][j + 2] + bias[n + 2];
            v4.w = acc[i][j + 3] + bias[n + 3];
            *(float4*)(out + (((size_t)(bb * H_ + h) * T_ + t) << 6) + d) = v4;
        }
    }
}

// ---------------- scores: per (b,h)  S = Q @ K^T * 0.125,  128x128 tiles, K=64 ------
__global__ __launch_bounds__(256) void scores_kernel(
    const float* __restrict__ Q, const float* __restrict__ K,
    float* __restrict__ S)
{
    const int bh = blockIdx.z;
    const int m0 = blockIdx.y * 128;
    const int n0 = blockIdx.x * 128;
    const float* Qb = Q + ((size_t)bh * T_ << 6);
    const float* Kb = K + ((size_t)bh * T_ << 6);
    __shared__ float Qs[64][128];   // [d][m]
    __shared__ float Ks[64][128];   // [d][n]
    const int tid = threadIdx.x;
    #pragma unroll
    for (int i = 0; i < 8; ++i) {
        int t = tid + i * 256;       // 0..2047
        int m  = t >> 4;             // 0..127
        int dq = (t & 15) << 2;      // 0..60
        float4 q4 = *(const float4*)(Qb + ((size_t)(m0 + m) << 6) + dq);
        Qs[dq + 0][m] = q4.x; Qs[dq + 1][m] = q4.y;
        Qs[dq + 2][m] = q4.z; Qs[dq + 3][m] = q4.w;
        float4 k4 = *(const float4*)(Kb + ((size_t)(n0 + m) << 6) + dq);
        Ks[dq + 0][m] = k4.x; Ks[dq + 1][m] = k4.y;
        Ks[dq + 2][m] = k4.z; Ks[dq + 3][m] = k4.w;
    }
    __syncthreads();
    const int tx = tid & 15, ty = tid >> 4;
    float acc[8][8] = {};
    #pragma unroll 4
    for (int d = 0; d < 64; ++d) {
        float a[8], b[8];
        *(float4*)&a[0] = *(const float4*)&Qs[d][ty * 8];
        *(float4*)&a[4] = *(const float4*)&Qs[d][ty * 8 + 4];
        *(float4*)&b[0] = *(const float4*)&Ks[d][tx * 8];
        *(float4*)&b[4] = *(const float4*)&Ks[d][tx * 8 + 4];
        #pragma unroll
        for (int i = 0; i < 8; ++i)
            #pragma unroll
            for (int j = 0; j < 8; ++j)
                acc[i][j] += a[i] * b[j];
    }
    float* Sb = S + (size_t)bh * T_ * T_;
    #pragma unroll
    for (int i = 0; i < 8; ++i) {
        int m = m0 + ty * 8 + i;
        #pragma unroll
        for (int j = 0; j < 8; j += 4) {
            int n = n0 + tx * 8 + j;
            float4 v4;
            v4.x = acc[i][j + 0] * 0.125f;
            v4.y = acc[i][j + 1] * 0.125f;
            v4.z = acc[i][j + 2] * 0.125f;
            v4.w = acc[i][j + 3] * 0.125f;
            *(float4*)(Sb + (size_t)m * T_ + n) = v4;
        }
    }
}

// ---------------- exact top-32 per row via 4-pass radix select --------------------
__device__ __forceinline__ uint32_t f2key(float f) {
    uint32_t u = __float_as_uint(f);
    return (u & 0x80000000u) ? ~u : (u | 0x80000000u);
}
__device__ __forceinline__ float key2f(uint32_t k) {
    uint32_t u = (k & 0x80000000u) ? (k ^ 0x80000000u) : ~k;
    return __uint_as_float(u);
}

__global__ __launch_bounds__(64) void topk_kernel(
    float* __restrict__ S, float* __restrict__ probs_c, int* __restrict__ idx_c)
{
    const size_t row = blockIdx.x;
    float* Srow = S + row * (size_t)T_;
    __shared__ int hist[256];
    __shared__ float selv[32];
    __shared__ int seli[32];
    __shared__ int bc_bin, bc_gt, cnt_gt;
    const int lane = threadIdx.x;

    uint32_t keys[32];
    #pragma unroll
    for (int c = 0; c < 8; ++c) {
        float4 v4 = *(const float4*)(Srow + c * 256 + lane * 4);
        keys[c * 4 + 0] = f2key(v4.x);
        keys[c * 4 + 1] = f2key(v4.y);
        keys[c * 4 + 2] = f2key(v4.z);
        keys[c * 4 + 3] = f2key(v4.w);
    }

    uint32_t prefix = 0;
    int kk = TOPK_;
    #pragma unroll
    for (int pass = 0; pass < 4; ++pass) {
        const int shift = 24 - pass * 8;
        hist[lane] = 0; hist[lane + 64] = 0; hist[lane + 128] = 0; hist[lane + 192] = 0;
        __syncthreads();
        #pragma unroll
        for (int e = 0; e < 32; ++e) {
            uint32_t key = keys[e];
            bool cand = (pass == 0) || (((key ^ prefix) >> (shift + 8)) == 0);
            if (cand) atomicAdd(&hist[(key >> shift) & 255], 1);
        }
        __syncthreads();
        int h0 = hist[lane * 4 + 0], h1 = hist[lane * 4 + 1];
        int h2 = hist[lane * 4 + 2], h3 = hist[lane * 4 + 3];
        int lsum = h0 + h1 + h2 + h3;
        int suf = lsum;
        #pragma unroll
        for (int off = 1; off < 64; off <<= 1) {
            int v = __shfl_down(suf, off);
            if (lane + off < 64) suf += v;
        }
        int a3 = suf - lsum;      // count of candidates in bins above lane*4+3
        int a2 = a3 + h3;
        int a1 = a2 + h2;
        int a0 = a1 + h1;
        if (a3 < kk && kk <= a3 + h3) { bc_bin = lane * 4 + 3; bc_gt = a3; }
        if (a2 < kk && kk <= a2 + h2) { bc_bin = lane * 4 + 2; bc_gt = a2; }
        if (a1 < kk && kk <= a1 + h1) { bc_bin = lane * 4 + 1; bc_gt = a1; }
        if (a0 < kk && kk <= a0 + h0) { bc_bin = lane * 4 + 0; bc_gt = a0; }
        __syncthreads();
        prefix |= ((uint32_t)bc_bin) << shift;
        kk -= bc_gt;
        __syncthreads();
    }
    // prefix = exact key of 32nd-largest; kk = #equals still needed (>=1)

    if (lane == 0) cnt_gt = 0;
    __syncthreads();
    int eq_local = 0;
    #pragma unroll
    for (int e = 0; e < 32; ++e) {
        uint32_t key = keys[e];
        if (key > prefix) {
            int p = atomicAdd(&cnt_gt, 1);
            if (p < 32) {
                selv[p] = key2f(key);
                seli[p] = (e >> 2) * 256 + lane * 4 + (e & 3);
            }
        } else if (key == prefix) {
            eq_local++;
        }
    }
    __syncthreads();
    const int G = cnt_gt;   // = 32 - kk
    int sc = eq_local;
    #pragma unroll
    for (int off = 1; off < 64; off <<= 1) {
        int v = __shfl_up(sc, off);
        if (lane >= off) sc += v;
    }
    int r = sc - eq_local;  // equals held by lower lanes
    #pragma unroll
    for (int e = 0; e < 32; ++e) {
        if (keys[e] == prefix) {
            if (r < kk && (G + r) < 32) {
                selv[G + r] = key2f(prefix);
                seli[G + r] = (e >> 2) * 256 + lane * 4 + (e & 3);
            }
            ++r;
        }
    }
    __syncthreads();

    // softmax over the 32 selected (lanes 0..31)
    float v = (lane < 32) ? selv[lane] : -3.0e38f;
    float mx = v;
    #pragma unroll
    for (int off = 16; off >= 1; off >>= 1)
        mx = fmaxf(mx, __shfl_xor(mx, off, 32));
    float ex = (lane < 32) ? expf(v - mx) : 0.0f;
    float sm = ex;
    #pragma unroll
    for (int off = 16; off >= 1; off >>= 1)
        sm += __shfl_xor(sm, off, 32);
    float p = ex / sm;
    if (lane < 32) {
        probs_c[row * 32 + lane] = p;
        idx_c[row * 32 + lane] = seli[lane];
        selv[lane] = p;
    }
    __syncthreads();

    // zero the row, then scatter the 32 probs (in place over the score scratch)
    float4 z4 = {0.f, 0.f, 0.f, 0.f};
    #pragma unroll
    for (int c = 0; c < 8; ++c)
        *(float4*)(Srow + c * 256 + lane * 4) = z4;
    __syncthreads();
    if (lane < 32) Srow[seli[lane]] = selv[lane];
}

// ---------------- sparse context: ctx[b,t,h*64+d] = sum_j p_j * V[bh, idx_j, d] ----
__global__ __launch_bounds__(256) void context_kernel(
    const float* __restrict__ V, const float* __restrict__ probs_c,
    const int* __restrict__ idx_c, float* __restrict__ ctx)
{
    const int wid = blockIdx.x * 4 + (threadIdx.x >> 6);
    const int lane = threadIdx.x & 63;
    const int bh = wid >> 11, t = wid & (T_ - 1);
    const float* Vb = V + ((size_t)bh * T_ << 6);
    const float* pr = probs_c + (size_t)wid * 32;
    const int* ir = idx_c + (size_t)wid * 32;
    float acc = 0.f;
    #pragma unroll 8
    for (int j = 0; j < 32; ++j) {
        float p = pr[j];
        int ix = ir[j];
        acc += p * Vb[((size_t)ix << 6) + lane];
    }
    const int b = bh >> 3, h = bh & 7;
    ctx[(size_t)(b * T_ + t) * C_ + h * 64 + lane] = acc;
}

// ---------------- Wo GEMM + bias -> analog (row-major) -----------------------------
__global__ __launch_bounds__(256) void wo_kernel(
    const float* __restrict__ A, const float* __restrict__ W,
    const float* __restrict__ bias, float* __restrict__ out)
{
    const int m0 = blockIdx.y * 128;
    const int n0 = blockIdx.x * 128;
    __shared__ float As[16][128];
    __shared__ float Bs[16][128];
    float acc[8][8] = {};
    const int tid = threadIdx.x;
    const int tx = tid & 15, ty = tid >> 4;

    for (int k0 = 0; k0 < C_; k0 += 16) {
        #pragma unroll
        for (int i = 0; i < 2; ++i) {
            int t = tid + i * 256;
            int m  = t >> 2;
            int kq = (t & 3) << 2;
            float4 a4 = *(const float4*)(A + (size_t)(m0 + m) * C_ + k0 + kq);
            As[kq + 0][m] = a4.x; As[kq + 1][m] = a4.y;
            As[kq + 2][m] = a4.z; As[kq + 3][m] = a4.w;
            int kk2 = t >> 5;
            int nq  = (t & 31) << 2;
            *(float4*)&Bs[kk2][nq] = *(const float4*)(W + (size_t)(k0 + kk2) * C_ + n0 + nq);
        }
        __syncthreads();
        #pragma unroll
        for (int k = 0; k < 16; ++k) {
            float a[8], b[8];
            *(float4*)&a[0] = *(const float4*)&As[k][ty * 8];
            *(float4*)&a[4] = *(const float4*)&As[k][ty * 8 + 4];
            *(float4*)&b[0] = *(const float4*)&Bs[k][tx * 8];
            *(float4*)&b[4] = *(const float4*)&Bs[k][tx * 8 + 4];
            #pragma unroll
            for (int i = 0; i < 8; ++i)
                #pragma unroll
                for (int j = 0; j < 8; ++j)
                    acc[i][j] += a[i] * b[j];
        }
        __syncthreads();
    }
    #pragma unroll
    for (int i = 0; i < 8; ++i) {
        int r = m0 + ty * 8 + i;
        #pragma unroll
        for (int j = 0; j < 8; j += 4) {
            int n = n0 + tx * 8 + j;
            float4 v4;
            v4.x = acc[i][j + 0] + bias[n + 0];
            v4.y = acc[i][j + 1] + bias[n + 1];
            v4.z = acc[i][j + 2] + bias[n + 2];
            v4.w = acc[i][j + 3] + bias[n + 3];
            *(float4*)(out + (size_t)r * C_ + n) = v4;
        }
    }
}

// ---------------- LayerNorm in place: one wave per row of 512 ----------------------
__global__ __launch_bounds__(256) void ln_kernel(
    float* __restrict__ a, const float* __restrict__ gamma, const float* __restrict__ beta)
{
    const int row = blockIdx.x * 4 + (threadIdx.x >> 6);
    const int lane = threadIdx.x & 63;
    float* ar = a + (size_t)row * C_;
    float x[8];
    *(float4*)&x[0] = *(const float4*)(ar + lane * 8);
    *(float4*)&x[4] = *(const float4*)(ar + lane * 8 + 4);
    float s = 0.f;
    #pragma unroll
    for (int i = 0; i < 8; ++i) s += x[i];
    #pragma unroll
    for (int off = 32; off >= 1; off >>= 1) s += __shfl_xor(s, off);
    float mu = s * (1.0f / C_);
    float vs = 0.f;
    #pragma unroll
    for (int i = 0; i < 8; ++i) { float d = x[i] - mu; vs += d * d; }
    #pragma unroll
    for (int off = 32; off >= 1; off >>= 1) vs += __shfl_xor(vs, off);
    float rs = rsqrtf(vs * (1.0f / C_) + 1e-5f);
    float g[8], bt[8];
    *(float4*)&g[0]  = *(const float4*)(gamma + lane * 8);
    *(float4*)&g[4]  = *(const float4*)(gamma + lane * 8 + 4);
    *(float4*)&bt[0] = *(const float4*)(beta + lane * 8);
    *(float4*)&bt[4] = *(const float4*)(beta + lane * 8 + 4);
    #pragma unroll
    for (int i = 0; i < 8; ++i) x[i] = (x[i] - mu) * rs * g[i] + bt[i];
    *(float4*)(ar + lane * 8)     = *(float4*)&x[0];
    *(float4*)(ar + lane * 8 + 4) = *(float4*)&x[4];
}

// ---------------- adaptive LIF scan, in place (analog -> spikes) -------------------
__global__ __launch_bounds__(256) void lif_kernel(float* __restrict__ a)
{
    const int idx = blockIdx.x * 256 + threadIdx.x;   // 0..2047 = (b, c)
    const int b = idx >> 9, c = idx & (C_ - 1);
    float* base = a + (size_t)b * T_ * C_ + c;
    float vmem = 0.f, adapt = 0.f;
    #pragma unroll 4
    for (int t = 0; t < T_; ++t) {
        float x = base[(size_t)t * C_];
        vmem = 0.9f * vmem + x;
        float th = 1.0f + 0.1f * adapt;
        float s = (vmem - th) > 0.f ? 1.f : 0.f;
        vmem -= s * th;
        adapt = 0.9f * adapt + s;
        base[(size_t)t * C_] = s;
    }
}

extern "C" void kernel_launch(void* const* d_in, const int* in_sizes, int n_in,
                              void* d_out, int out_size, void* d_ws, size_t ws_size,
                              hipStream_t stream)
{
    const float* x     = (const float*)d_in[0];
    const float* Wq    = (const float*)d_in[1];
    const float* bq    = (const float*)d_in[2];
    const float* Wk    = (const float*)d_in[3];
    const float* bk    = (const float*)d_in[4];
    const float* Wv    = (const float*)d_in[5];
    const float* bv    = (const float*)d_in[6];
    const float* Wo    = (const float*)d_in[7];
    const float* bo    = (const float*)d_in[8];
    const float* gamma = (const float*)d_in[9];
    const float* beta  = (const float*)d_in[10];

    float* out    = (float*)d_out;
    float* spikes = out;                                   // B*T*C (also analog scratch)
    float* probs  = out + (size_t)B_ * T_ * C_;            // B*H*T*T (also score scratch)

    float* ws = (float*)d_ws;
    const size_t NQ = (size_t)B_ * H_ * T_ * HD_;          // 4194304
    float* Qb      = ws;
    float* Kb      = ws + NQ;
    float* Vb      = ws + 2 * NQ;
    float* ctx     = ws + 3 * NQ;
    float* probs_c = ws + 4 * NQ;                          // ROWS_*32
    int*   idx_c   = (int*)(ws + 4 * NQ + (size_t)ROWS_ * 32);

    qkv_kernel<<<dim3(4, 64, 3), 256, 0, stream>>>(x, Wq, bq, Wk, bk, Wv, bv, Qb, Kb, Vb);
    scores_kernel<<<dim3(16, 16, 32), 256, 0, stream>>>(Qb, Kb, probs);
    topk_kernel<<<dim3(ROWS_), 64, 0, stream>>>(probs, probs_c, idx_c);
    context_kernel<<<dim3(ROWS_ / 4), 256, 0, stream>>>(Vb, probs_c, idx_c, ctx);
    wo_kernel<<<dim3(4, 64), 256, 0, stream>>>(ctx, Wo, bo, spikes);
    ln_kernel<<<dim3(BT_ / 4), 256, 0, stream>>>(spikes, gamma, beta);
    lif_kernel<<<dim3(8), 256, 0, stream>>>(spikes);
}

// Round 2
// 1421.336 us; speedup vs baseline: 1.2911x; 1.2911x over previous
//
#include <hip/hip_runtime.h>
#include <cstdint>
#include <math.h>

#define B_ 4
#define T_ 2048
#define C_ 512
#define H_ 8
#define HD_ 64
#define TOPK_ 32
#define ROWS_ (B_*H_*T_)   /* 65536 */
#define BT_ (B_*T_)        /* 8192 */

// ---------------- QKV projection GEMM: (8192x512)@(512x512), head-layout out --------
__global__ __launch_bounds__(256) void qkv_kernel(
    const float* __restrict__ x,
    const float* __restrict__ Wq, const float* __restrict__ bq,
    const float* __restrict__ Wk, const float* __restrict__ bk,
    const float* __restrict__ Wv, const float* __restrict__ bv,
    float* __restrict__ Q, float* __restrict__ K, float* __restrict__ V)
{
    const int which = blockIdx.z;
    const float* W    = (which == 0) ? Wq : (which == 1) ? Wk : Wv;
    const float* bias = (which == 0) ? bq : (which == 1) ? bk : bv;
    float* out        = (which == 0) ? Q  : (which == 1) ? K  : V;

    const int m0 = blockIdx.y * 128;
    const int n0 = blockIdx.x * 128;
    __shared__ float As[16][128];   // [k][m] transposed
    __shared__ float Bs[16][128];   // [k][n]
    float acc[8][8] = {};
    const int tid = threadIdx.x;
    const int tx = tid & 15, ty = tid >> 4;

    for (int k0 = 0; k0 < C_; k0 += 16) {
        #pragma unroll
        for (int i = 0; i < 2; ++i) {
            int t = tid + i * 256;           // 0..511
            int m  = t >> 2;                 // 0..127
            int kq = (t & 3) << 2;           // 0,4,8,12
            float4 a4 = *(const float4*)(x + (size_t)(m0 + m) * C_ + k0 + kq);
            As[kq + 0][m] = a4.x; As[kq + 1][m] = a4.y;
            As[kq + 2][m] = a4.z; As[kq + 3][m] = a4.w;
            int kk2 = t >> 5;                // 0..15
            int nq  = (t & 31) << 2;         // 0..124
            *(float4*)&Bs[kk2][nq] = *(const float4*)(W + (size_t)(k0 + kk2) * C_ + n0 + nq);
        }
        __syncthreads();
        #pragma unroll
        for (int k = 0; k < 16; ++k) {
            float a[8], b[8];
            *(float4*)&a[0] = *(const float4*)&As[k][ty * 8];
            *(float4*)&a[4] = *(const float4*)&As[k][ty * 8 + 4];
            *(float4*)&b[0] = *(const float4*)&Bs[k][tx * 8];
            *(float4*)&b[4] = *(const float4*)&Bs[k][tx * 8 + 4];
            #pragma unroll
            for (int i = 0; i < 8; ++i)
                #pragma unroll
                for (int j = 0; j < 8; ++j)
                    acc[i][j] += a[i] * b[j];
        }
        __syncthreads();
    }
    #pragma unroll
    for (int i = 0; i < 8; ++i) {
        int r = m0 + ty * 8 + i;
        int bb = r >> 11, t = r & (T_ - 1);
        #pragma unroll
        for (int j = 0; j < 8; j += 4) {
            int n = n0 + tx * 8 + j;
            int h = n >> 6, d = n & 63;
            float4 v4;
            v4.x = acc[i][j + 0] + bias[n + 0];
            v4.y = acc[i][j + 1] + bias[n + 1];
            v4.z = acc[i][j + 2] + bias[n + 2];
            v4.w = acc[i][j + 3] + bias[n + 3];
            *(float4*)(out + (((size_t)(bb * H_ + h) * T_ + t) << 6) + d) = v4;
        }
    }
}

// ---------------- scores: per (b,h)  S = Q @ K^T * 0.125,  128x128 tiles, K=64 ------
__global__ __launch_bounds__(256) void scores_kernel(
    const float* __restrict__ Q, const float* __restrict__ K,
    float* __restrict__ S)
{
    const int bh = blockIdx.z;
    const int m0 = blockIdx.y * 128;
    const int n0 = blockIdx.x * 128;
    const float* Qb = Q + ((size_t)bh * T_ << 6);
    const float* Kb = K + ((size_t)bh * T_ << 6);
    __shared__ float Qs[64][128];   // [d][m]
    __shared__ float Ks[64][128];   // [d][n]
    const int tid = threadIdx.x;
    #pragma unroll
    for (int i = 0; i < 8; ++i) {
        int t = tid + i * 256;       // 0..2047
        int m  = t >> 4;             // 0..127
        int dq = (t & 15) << 2;      // 0..60
        float4 q4 = *(const float4*)(Qb + ((size_t)(m0 + m) << 6) + dq);
        Qs[dq + 0][m] = q4.x; Qs[dq + 1][m] = q4.y;
        Qs[dq + 2][m] = q4.z; Qs[dq + 3][m] = q4.w;
        float4 k4 = *(const float4*)(Kb + ((size_t)(n0 + m) << 6) + dq);
        Ks[dq + 0][m] = k4.x; Ks[dq + 1][m] = k4.y;
        Ks[dq + 2][m] = k4.z; Ks[dq + 3][m] = k4.w;
    }
    __syncthreads();
    const int tx = tid & 15, ty = tid >> 4;
    float acc[8][8] = {};
    #pragma unroll 4
    for (int d = 0; d < 64; ++d) {
        float a[8], b[8];
        *(float4*)&a[0] = *(const float4*)&Qs[d][ty * 8];
        *(float4*)&a[4] = *(const float4*)&Qs[d][ty * 8 + 4];
        *(float4*)&b[0] = *(const float4*)&Ks[d][tx * 8];
        *(float4*)&b[4] = *(const float4*)&Ks[d][tx * 8 + 4];
        #pragma unroll
        for (int i = 0; i < 8; ++i)
            #pragma unroll
            for (int j = 0; j < 8; ++j)
                acc[i][j] += a[i] * b[j];
    }
    float* Sb = S + (size_t)bh * T_ * T_;
    #pragma unroll
    for (int i = 0; i < 8; ++i) {
        int m = m0 + ty * 8 + i;
        #pragma unroll
        for (int j = 0; j < 8; j += 4) {
            int n = n0 + tx * 8 + j;
            float4 v4;
            v4.x = acc[i][j + 0] * 0.125f;
            v4.y = acc[i][j + 1] * 0.125f;
            v4.z = acc[i][j + 2] * 0.125f;
            v4.w = acc[i][j + 3] * 0.125f;
            *(float4*)(Sb + (size_t)m * T_ + n) = v4;
        }
    }
}

// ---------------- exact top-32 per row via 4-pass radix select --------------------
__device__ __forceinline__ uint32_t f2key(float f) {
    uint32_t u = __float_as_uint(f);
    return (u & 0x80000000u) ? ~u : (u | 0x80000000u);
}
__device__ __forceinline__ float key2f(uint32_t k) {
    uint32_t u = (k & 0x80000000u) ? (k ^ 0x80000000u) : ~k;
    return __uint_as_float(u);
}

__global__ __launch_bounds__(64) void topk_kernel(
    float* __restrict__ S, float* __restrict__ probs_c, int* __restrict__ idx_c)
{
    const size_t row = blockIdx.x;
    float* Srow = S + row * (size_t)T_;
    __shared__ int hist[256];
    __shared__ float selv[32];
    __shared__ int seli[32];
    __shared__ int bc_bin, bc_gt, cnt_gt;
    const int lane = threadIdx.x;

    uint32_t keys[32];
    #pragma unroll
    for (int c = 0; c < 8; ++c) {
        float4 v4 = *(const float4*)(Srow + c * 256 + lane * 4);
        keys[c * 4 + 0] = f2key(v4.x);
        keys[c * 4 + 1] = f2key(v4.y);
        keys[c * 4 + 2] = f2key(v4.z);
        keys[c * 4 + 3] = f2key(v4.w);
    }

    uint32_t prefix = 0;
    int kk = TOPK_;
    #pragma unroll
    for (int pass = 0; pass < 4; ++pass) {
        const int shift = 24 - pass * 8;
        hist[lane] = 0; hist[lane + 64] = 0; hist[lane + 128] = 0; hist[lane + 192] = 0;
        __syncthreads();
        #pragma unroll
        for (int e = 0; e < 32; ++e) {
            uint32_t key = keys[e];
            bool cand = (pass == 0) || (((key ^ prefix) >> (shift + 8)) == 0);
            if (cand) atomicAdd(&hist[(key >> shift) & 255], 1);
        }
        __syncthreads();
        int h0 = hist[lane * 4 + 0], h1 = hist[lane * 4 + 1];
        int h2 = hist[lane * 4 + 2], h3 = hist[lane * 4 + 3];
        int lsum = h0 + h1 + h2 + h3;
        int suf = lsum;
        #pragma unroll
        for (int off = 1; off < 64; off <<= 1) {
            int v = __shfl_down(suf, off);
            if (lane + off < 64) suf += v;
        }
        int a3 = suf - lsum;      // count of candidates in bins above lane*4+3
        int a2 = a3 + h3;
        int a1 = a2 + h2;
        int a0 = a1 + h1;
        if (a3 < kk && kk <= a3 + h3) { bc_bin = lane * 4 + 3; bc_gt = a3; }
        if (a2 < kk && kk <= a2 + h2) { bc_bin = lane * 4 + 2; bc_gt = a2; }
        if (a1 < kk && kk <= a1 + h1) { bc_bin = lane * 4 + 1; bc_gt = a1; }
        if (a0 < kk && kk <= a0 + h0) { bc_bin = lane * 4 + 0; bc_gt = a0; }
        __syncthreads();
        prefix |= ((uint32_t)bc_bin) << shift;
        kk -= bc_gt;
        __syncthreads();
    }
    // prefix = exact key of 32nd-largest; kk = #equals still needed (>=1)

    if (lane == 0) cnt_gt = 0;
    __syncthreads();
    int eq_local = 0;
    #pragma unroll
    for (int e = 0; e < 32; ++e) {
        uint32_t key = keys[e];
        if (key > prefix) {
            int p = atomicAdd(&cnt_gt, 1);
            if (p < 32) {
                selv[p] = key2f(key);
                seli[p] = (e >> 2) * 256 + lane * 4 + (e & 3);
            }
        } else if (key == prefix) {
            eq_local++;
        }
    }
    __syncthreads();
    const int G = cnt_gt;   // = 32 - kk
    int sc = eq_local;
    #pragma unroll
    for (int off = 1; off < 64; off <<= 1) {
        int v = __shfl_up(sc, off);
        if (lane >= off) sc += v;
    }
    int r = sc - eq_local;  // equals held by lower lanes
    #pragma unroll
    for (int e = 0; e < 32; ++e) {
        if (keys[e] == prefix) {
            if (r < kk && (G + r) < 32) {
                selv[G + r] = key2f(prefix);
                seli[G + r] = (e >> 2) * 256 + lane * 4 + (e & 3);
            }
            ++r;
        }
    }
    __syncthreads();

    // softmax over the 32 selected (lanes 0..31)
    float v = (lane < 32) ? selv[lane] : -3.0e38f;
    float mx = v;
    #pragma unroll
    for (int off = 16; off >= 1; off >>= 1)
        mx = fmaxf(mx, __shfl_xor(mx, off, 32));
    float ex = (lane < 32) ? expf(v - mx) : 0.0f;
    float sm = ex;
    #pragma unroll
    for (int off = 16; off >= 1; off >>= 1)
        sm += __shfl_xor(sm, off, 32);
    float p = ex / sm;
    if (lane < 32) {
        probs_c[row * 32 + lane] = p;
        idx_c[row * 32 + lane] = seli[lane];
        selv[lane] = p;
    }
    __syncthreads();

    // zero the row, then scatter the 32 probs (in place over the score scratch)
    float4 z4 = {0.f, 0.f, 0.f, 0.f};
    #pragma unroll
    for (int c = 0; c < 8; ++c)
        *(float4*)(Srow + c * 256 + lane * 4) = z4;
    __syncthreads();
    if (lane < 32) Srow[seli[lane]] = selv[lane];
}

// ---------------- sparse context: ctx[b,t,h*64+d] = sum_j p_j * V[bh, idx_j, d] ----
__global__ __launch_bounds__(256) void context_kernel(
    const float* __restrict__ V, const float* __restrict__ probs_c,
    const int* __restrict__ idx_c, float* __restrict__ ctx)
{
    const int wid = blockIdx.x * 4 + (threadIdx.x >> 6);
    const int lane = threadIdx.x & 63;
    const int bh = wid >> 11, t = wid & (T_ - 1);
    const float* Vb = V + ((size_t)bh * T_ << 6);
    const float* pr = probs_c + (size_t)wid * 32;
    const int* ir = idx_c + (size_t)wid * 32;
    float acc = 0.f;
    #pragma unroll 8
    for (int j = 0; j < 32; ++j) {
        float p = pr[j];
        int ix = ir[j];
        acc += p * Vb[((size_t)ix << 6) + lane];
    }
    const int b = bh >> 3, h = bh & 7;
    ctx[(size_t)(b * T_ + t) * C_ + h * 64 + lane] = acc;
}

// ---------------- Wo GEMM + bias -> analog (row-major) -----------------------------
__global__ __launch_bounds__(256) void wo_kernel(
    const float* __restrict__ A, const float* __restrict__ W,
    const float* __restrict__ bias, float* __restrict__ out)
{
    const int m0 = blockIdx.y * 128;
    const int n0 = blockIdx.x * 128;
    __shared__ float As[16][128];
    __shared__ float Bs[16][128];
    float acc[8][8] = {};
    const int tid = threadIdx.x;
    const int tx = tid & 15, ty = tid >> 4;

    for (int k0 = 0; k0 < C_; k0 += 16) {
        #pragma unroll
        for (int i = 0; i < 2; ++i) {
            int t = tid + i * 256;
            int m  = t >> 2;
            int kq = (t & 3) << 2;
            float4 a4 = *(const float4*)(A + (size_t)(m0 + m) * C_ + k0 + kq);
            As[kq + 0][m] = a4.x; As[kq + 1][m] = a4.y;
            As[kq + 2][m] = a4.z; As[kq + 3][m] = a4.w;
            int kk2 = t >> 5;
            int nq  = (t & 31) << 2;
            *(float4*)&Bs[kk2][nq] = *(const float4*)(W + (size_t)(k0 + kk2) * C_ + n0 + nq);
        }
        __syncthreads();
        #pragma unroll
        for (int k = 0; k < 16; ++k) {
            float a[8], b[8];
            *(float4*)&a[0] = *(const float4*)&As[k][ty * 8];
            *(float4*)&a[4] = *(const float4*)&As[k][ty * 8 + 4];
            *(float4*)&b[0] = *(const float4*)&Bs[k][tx * 8];
            *(float4*)&b[4] = *(const float4*)&Bs[k][tx * 8 + 4];
            #pragma unroll
            for (int i = 0; i < 8; ++i)
                #pragma unroll
                for (int j = 0; j < 8; ++j)
                    acc[i][j] += a[i] * b[j];
        }
        __syncthreads();
    }
    #pragma unroll
    for (int i = 0; i < 8; ++i) {
        int r = m0 + ty * 8 + i;
        #pragma unroll
        for (int j = 0; j < 8; j += 4) {
            int n = n0 + tx * 8 + j;
            float4 v4;
            v4.x = acc[i][j + 0] + bias[n + 0];
            v4.y = acc[i][j + 1] + bias[n + 1];
            v4.z = acc[i][j + 2] + bias[n + 2];
            v4.w = acc[i][j + 3] + bias[n + 3];
            *(float4*)(out + (size_t)r * C_ + n) = v4;
        }
    }
}

// ---------------- LayerNorm in place: one wave per row of 512 ----------------------
__global__ __launch_bounds__(256) void ln_kernel(
    float* __restrict__ a, const float* __restrict__ gamma, const float* __restrict__ beta)
{
    const int row = blockIdx.x * 4 + (threadIdx.x >> 6);
    const int lane = threadIdx.x & 63;
    float* ar = a + (size_t)row * C_;
    float x[8];
    *(float4*)&x[0] = *(const float4*)(ar + lane * 8);
    *(float4*)&x[4] = *(const float4*)(ar + lane * 8 + 4);
    float s = 0.f;
    #pragma unroll
    for (int i = 0; i < 8; ++i) s += x[i];
    #pragma unroll
    for (int off = 32; off >= 1; off >>= 1) s += __shfl_xor(s, off);
    float mu = s * (1.0f / C_);
    float vs = 0.f;
    #pragma unroll
    for (int i = 0; i < 8; ++i) { float d = x[i] - mu; vs += d * d; }
    #pragma unroll
    for (int off = 32; off >= 1; off >>= 1) vs += __shfl_xor(vs, off);
    float rs = rsqrtf(vs * (1.0f / C_) + 1e-5f);
    float g[8], bt[8];
    *(float4*)&g[0]  = *(const float4*)(gamma + lane * 8);
    *(float4*)&g[4]  = *(const float4*)(gamma + lane * 8 + 4);
    *(float4*)&bt[0] = *(const float4*)(beta + lane * 8);
    *(float4*)&bt[4] = *(const float4*)(beta + lane * 8 + 4);
    #pragma unroll
    for (int i = 0; i < 8; ++i) x[i] = (x[i] - mu) * rs * g[i] + bt[i];
    *(float4*)(ar + lane * 8)     = *(float4*)&x[0];
    *(float4*)(ar + lane * 8 + 4) = *(float4*)&x[4];
}

// ---------------- adaptive LIF scan, in place (analog -> spikes) -------------------
// 2048 independent (b,c) chains -> 32 single-wave blocks spread over 32 CUs.
// Loads batched 32-deep + double-buffered in registers: the recurrence critical
// path (~16 cyc/step) overlaps the ~500-900 cyc memory latency of the next batch.
#define LIF_BATCH 32
__global__ __launch_bounds__(64) void lif_kernel(float* __restrict__ a)
{
    const int wid = blockIdx.x;                 // 0..31
    const int b = wid >> 3;
    const int c = ((wid & 7) << 6) | threadIdx.x;
    float* base = a + (size_t)b * T_ * C_ + c;

    float xb[2][LIF_BATCH];
    #pragma unroll
    for (int j = 0; j < LIF_BATCH; ++j)
        xb[0][j] = base[(size_t)j * C_];

    float vmem = 0.f, adapt = 0.f;
    #pragma unroll 1
    for (int t0 = 0; t0 < T_; t0 += LIF_BATCH) {
        const int cur = (t0 / LIF_BATCH) & 1;
        if (t0 + LIF_BATCH < T_) {
            #pragma unroll
            for (int j = 0; j < LIF_BATCH; ++j)
                xb[cur ^ 1][j] = base[(size_t)(t0 + LIF_BATCH + j) * C_];
        }
        #pragma unroll
        for (int j = 0; j < LIF_BATCH; ++j) {
            float x = xb[cur][j];
            vmem = fmaf(0.9f, vmem, x);
            float th = fmaf(0.1f, adapt, 1.0f);
            float s = (vmem - th) > 0.f ? 1.f : 0.f;
            vmem -= s * th;
            adapt = fmaf(0.9f, adapt, s);
            xb[cur][j] = s;
        }
        #pragma unroll
        for (int j = 0; j < LIF_BATCH; ++j)
            base[(size_t)(t0 + j) * C_] = xb[cur][j];
    }
}

extern "C" void kernel_launch(void* const* d_in, const int* in_sizes, int n_in,
                              void* d_out, int out_size, void* d_ws, size_t ws_size,
                              hipStream_t stream)
{
    const float* x     = (const float*)d_in[0];
    const float* Wq    = (const float*)d_in[1];
    const float* bq    = (const float*)d_in[2];
    const float* Wk    = (const float*)d_in[3];
    const float* bk    = (const float*)d_in[4];
    const float* Wv    = (const float*)d_in[5];
    const float* bv    = (const float*)d_in[6];
    const float* Wo    = (const float*)d_in[7];
    const float* bo    = (const float*)d_in[8];
    const float* gamma = (const float*)d_in[9];
    const float* beta  = (const float*)d_in[10];

    float* out    = (float*)d_out;
    float* spikes = out;                                   // B*T*C (also analog scratch)
    float* probs  = out + (size_t)B_ * T_ * C_;            // B*H*T*T (also score scratch)

    float* ws = (float*)d_ws;
    const size_t NQ = (size_t)B_ * H_ * T_ * HD_;          // 4194304
    float* Qb      = ws;
    float* Kb      = ws + NQ;
    float* Vb      = ws + 2 * NQ;
    float* ctx     = ws + 3 * NQ;
    float* probs_c = ws + 4 * NQ;                          // ROWS_*32
    int*   idx_c   = (int*)(ws + 4 * NQ + (size_t)ROWS_ * 32);

    qkv_kernel<<<dim3(4, 64, 3), 256, 0, stream>>>(x, Wq, bq, Wk, bk, Wv, bv, Qb, Kb, Vb);
    scores_kernel<<<dim3(16, 16, 32), 256, 0, stream>>>(Qb, Kb, probs);
    topk_kernel<<<dim3(ROWS_), 64, 0, stream>>>(probs, probs_c, idx_c);
    context_kernel<<<dim3(ROWS_ / 4), 256, 0, stream>>>(Vb, probs_c, idx_c, ctx);
    wo_kernel<<<dim3(4, 64), 256, 0, stream>>>(ctx, Wo, bo, spikes);
    ln_kernel<<<dim3(BT_ / 4), 256, 0, stream>>>(spikes, gamma, beta);
    lif_kernel<<<dim3(32), 64, 0, stream>>>(spikes);
}